// Round 1
// baseline (231.427 us; speedup 1.0000x reference)
//
#include <hip/hip_runtime.h>
#include <math.h>

#define LEN_Q 13294
#define NFRAMES 2
#define MTOT (LEN_Q * NFRAMES)   // 26588
#define HEADS 8
#define LEVELS 4
#define POINTS 4

typedef __attribute__((ext_vector_type(8))) short short8;
typedef __attribute__((ext_vector_type(4))) float f32x4;
typedef __attribute__((ext_vector_type(2))) unsigned int uint2v;
typedef __attribute__((ext_vector_type(4))) unsigned short ushort4v;

__device__ __forceinline__ unsigned short f2bf(float x) {
    unsigned u = __builtin_bit_cast(unsigned, x);
    unsigned r = (u + 0x7fffu + ((u >> 16) & 1u)) >> 16;
    return (unsigned short)r;
}
__device__ __forceinline__ float bf2f(unsigned short b) {
    return __builtin_bit_cast(float, (unsigned)b << 16);
}

#define LSTR 40   // LDS row stride (shorts)

// ---------------------------------------------------------------------------
// prep: all 4 weight transposes f32[K,N] -> bf16[N,K] in one dispatch.
// ---------------------------------------------------------------------------
__global__ __launch_bounds__(256) void prep_weights(
    const float* __restrict__ Wv,  const float* __restrict__ Woff,
    const float* __restrict__ Wat, const float* __restrict__ Wout,
    unsigned short* __restrict__ wvT,   // 256x256
    unsigned short* __restrict__ woaT,  // 384x256
    unsigned short* __restrict__ woutT) // 256x256
{
    const int b = blockIdx.x;
    const int k = threadIdx.x;
    const float* src; unsigned short* dst; int N; int n;
    if (b < 256)      { src = Wv;   dst = wvT;          N = 256; n = b; }
    else if (b < 512) { src = Woff; dst = woaT;         N = 256; n = b - 256; }
    else if (b < 640) { src = Wat;  dst = woaT + 65536; N = 128; n = b - 512; }
    else              { src = Wout; dst = woutT;        N = 256; n = b - 640; }
    dst[(size_t)n * 256 + k] = f2bf(src[(size_t)k * N + n]);
}

// ---------------------------------------------------------------------------
// Fused GEMM (R9: R5 structure + register prefetch pipeline — kept, it won).
// ---------------------------------------------------------------------------
__global__ __launch_bounds__(256, 3) void gemm_fused(
    const float* __restrict__ Aval,
    const float* __restrict__ Aq,
    const unsigned short* __restrict__ BTv,   // [256,256]
    const unsigned short* __restrict__ BToa,  // [384,256]
    const float* __restrict__ bv,
    const float* __restrict__ boff,
    const float* __restrict__ battn,
    unsigned short* __restrict__ v16,
    unsigned short* __restrict__ off16,
    unsigned short* __restrict__ at16,
    int M, int K)
{
    __shared__ unsigned short As[128 * LSTR];
    __shared__ unsigned short Bs[128 * LSTR];

    const int t = threadIdx.x;
    const int w = t >> 6;
    const int L = t & 63;
    const int m0 = blockIdx.y * 128;
    const bool isVal = (blockIdx.x < 2);
    const int nTile = isVal ? blockIdx.x : blockIdx.x - 2;
    const float* Af = isVal ? Aval : Aq;
    const unsigned short* BTb = (isVal ? BTv : BToa) + (size_t)nTile * 128 * K;

    const int sr = t >> 1;
    const int sc = (t & 1) * 16;
    int arow = m0 + sr; if (arow > M - 1) arow = M - 1;
    const float* Ag = Af + (size_t)arow * K + sc;
    const unsigned short* Bg = BTb + (size_t)sr * K + sc;
    unsigned short* AsW = &As[sr * LSTR + sc];
    unsigned short* BsW = &Bs[sr * LSTR + sc];

    const int mq = (w & 1) * 64;
    const int nq = (w >> 1) * 64;
    const int lr = L & 15;
    const int kq = (L >> 4) * 8;

    f32x4 acc[4][4];
    #pragma unroll
    for (int i = 0; i < 4; ++i)
        #pragma unroll
        for (int j = 0; j < 4; ++j) acc[i][j] = (f32x4){0.f, 0.f, 0.f, 0.f};

    f32x4 a0 = *(const f32x4*)(Ag);
    f32x4 a1 = *(const f32x4*)(Ag + 4);
    f32x4 a2 = *(const f32x4*)(Ag + 8);
    f32x4 a3 = *(const f32x4*)(Ag + 12);
    short8 b0 = *(const short8*)(Bg);
    short8 b1 = *(const short8*)(Bg + 8);

    for (int k0 = 0; k0 < K; k0 += 32) {
        short8 p0, p1;
        p0[0]=(short)f2bf(a0.x); p0[1]=(short)f2bf(a0.y); p0[2]=(short)f2bf(a0.z); p0[3]=(short)f2bf(a0.w);
        p0[4]=(short)f2bf(a1.x); p0[5]=(short)f2bf(a1.y); p0[6]=(short)f2bf(a1.z); p0[7]=(short)f2bf(a1.w);
        p1[0]=(short)f2bf(a2.x); p1[1]=(short)f2bf(a2.y); p1[2]=(short)f2bf(a2.z); p1[3]=(short)f2bf(a2.w);
        p1[4]=(short)f2bf(a3.x); p1[5]=(short)f2bf(a3.y); p1[6]=(short)f2bf(a3.z); p1[7]=(short)f2bf(a3.w);
        __syncthreads();
        *(short8*)(AsW) = p0;
        *(short8*)(AsW + 8) = p1;
        *(short8*)(BsW) = b0;
        *(short8*)(BsW + 8) = b1;
        __syncthreads();

        if (k0 + 32 < K) {              // prefetch next tile (reg-private)
            a0 = *(const f32x4*)(Ag + k0 + 32);
            a1 = *(const f32x4*)(Ag + k0 + 36);
            a2 = *(const f32x4*)(Ag + k0 + 40);
            a3 = *(const f32x4*)(Ag + k0 + 44);
            b0 = *(const short8*)(Bg + k0 + 32);
            b1 = *(const short8*)(Bg + k0 + 40);
        }

        short8 af[4], bf[4];
        #pragma unroll
        for (int i = 0; i < 4; ++i)
            af[i] = *(const short8*)&As[(mq + i * 16 + lr) * LSTR + kq];
        #pragma unroll
        for (int j = 0; j < 4; ++j)
            bf[j] = *(const short8*)&Bs[(nq + j * 16 + lr) * LSTR + kq];
        #pragma unroll
        for (int i = 0; i < 4; ++i)
            #pragma unroll
            for (int j = 0; j < 4; ++j)
                acc[i][j] = __builtin_amdgcn_mfma_f32_16x16x32_bf16(af[i], bf[j], acc[i][j], 0, 0, 0);
    }

    const int rr = (L >> 4) * 4;
    #pragma unroll
    for (int i = 0; i < 4; ++i) {
        #pragma unroll
        for (int r = 0; r < 4; ++r) {
            int m = m0 + mq + i * 16 + rr + r;
            if (m < M) {
                #pragma unroll
                for (int j = 0; j < 4; ++j) {
                    int colg = nTile * 128 + nq + j * 16 + lr;
                    float v = acc[i][j][r];
                    if (isVal) {
                        v16[(size_t)m * 256 + colg] = f2bf(v + bv[colg]);
                    } else if (colg < 256) {
                        off16[(size_t)m * 256 + colg] = f2bf(v + boff[colg]);
                    } else {
                        at16[(size_t)m * 128 + (colg - 256)] = f2bf(v + battn[colg - 256]);
                    }
                }
            }
        }
    }
}

// ---------------------------------------------------------------------------
// Output GEMM (R9 register-prefetch version — kept).
// ---------------------------------------------------------------------------
__global__ __launch_bounds__(256, 3) void gemm_out(
    const unsigned short* __restrict__ A,
    const unsigned short* __restrict__ BT,
    const float* __restrict__ bias,
    float* __restrict__ C,
    int M, int K)
{
    __shared__ unsigned short As[128 * LSTR];
    __shared__ unsigned short Bs[128 * LSTR];

    const int t = threadIdx.x;
    const int w = t >> 6;
    const int L = t & 63;
    const int m0 = blockIdx.y * 128;
    const int n0 = blockIdx.x * 128;

    const int sr = t >> 1;
    const int sc = (t & 1) * 16;
    int arow = m0 + sr; if (arow > M - 1) arow = M - 1;
    const unsigned short* Ag = A + (size_t)arow * K + sc;
    const unsigned short* Bg = BT + (size_t)(n0 + sr) * K + sc;
    unsigned short* AsW = &As[sr * LSTR + sc];
    unsigned short* BsW = &Bs[sr * LSTR + sc];

    const int mq = (w & 1) * 64;
    const int nq = (w >> 1) * 64;
    const int lr = L & 15;
    const int kq = (L >> 4) * 8;

    f32x4 acc[4][4];
    #pragma unroll
    for (int i = 0; i < 4; ++i)
        #pragma unroll
        for (int j = 0; j < 4; ++j) acc[i][j] = (f32x4){0.f, 0.f, 0.f, 0.f};

    short8 a0 = *(const short8*)(Ag);
    short8 a1 = *(const short8*)(Ag + 8);
    short8 b0 = *(const short8*)(Bg);
    short8 b1 = *(const short8*)(Bg + 8);

    for (int k0 = 0; k0 < K; k0 += 32) {
        __syncthreads();
        *(short8*)(AsW) = a0;
        *(short8*)(AsW + 8) = a1;
        *(short8*)(BsW) = b0;
        *(short8*)(BsW + 8) = b1;
        __syncthreads();

        if (k0 + 32 < K) {
            a0 = *(const short8*)(Ag + k0 + 32);
            a1 = *(const short8*)(Ag + k0 + 40);
            b0 = *(const short8*)(Bg + k0 + 32);
            b1 = *(const short8*)(Bg + k0 + 40);
        }

        short8 af[4], bf[4];
        #pragma unroll
        for (int i = 0; i < 4; ++i)
            af[i] = *(const short8*)&As[(mq + i * 16 + lr) * LSTR + kq];
        #pragma unroll
        for (int j = 0; j < 4; ++j)
            bf[j] = *(const short8*)&Bs[(nq + j * 16 + lr) * LSTR + kq];
        #pragma unroll
        for (int i = 0; i < 4; ++i)
            #pragma unroll
            for (int j = 0; j < 4; ++j)
                acc[i][j] = __builtin_amdgcn_mfma_f32_16x16x32_bf16(af[i], bf[j], acc[i][j], 0, 0, 0);
    }

    const int rr = (L >> 4) * 4;
    #pragma unroll
    for (int i = 0; i < 4; ++i) {
        #pragma unroll
        for (int r = 0; r < 4; ++r) {
            int m = m0 + mq + i * 16 + rr + r;
            if (m < M) {
                #pragma unroll
                for (int j = 0; j < 4; ++j) {
                    int n = n0 + nq + j * 16 + lr;
                    C[(size_t)m * 256 + n] = acc[i][j][r] + bias[n];
                }
            }
        }
    }
}

// ---------------------------------------------------------------------------
// Sampler v8: head-partitioned for XCD-L2 residency.
//   head = blockIdx.x & 7  -> lands on one XCD (round-robin dispatch).
//   Each block: 32 rows x 1 head. Per-head value slice = 26588 x 64 B
//   = 1.7 MB, fits the 4 MB XCD L2 -> corner gathers hit local L2 instead
//   of Infinity Cache.
//   Per-output-element FMA order is bit-identical to sample7; only the
//   softmax sum becomes an 8-lane shuffle tree (fp32 reorder, ~1 ulp).
// ---------------------------------------------------------------------------
__global__ __launch_bounds__(256) void sample8(
    const unsigned short* __restrict__ value,  // bf16 [MTOT,256]
    const unsigned short* __restrict__ off,    // bf16 [MTOT,256]
    const unsigned short* __restrict__ attn,   // bf16 [MTOT,128]
    const float* __restrict__ refpts,          // [LEN_Q, LEVELS, 2]
    const int*   __restrict__ spatial,         // [LEVELS,2] (H,W)
    const int*   __restrict__ lsi,             // [LEVELS]
    unsigned short* __restrict__ samp)         // bf16 [MTOT,256]
{
    const int b = blockIdx.x;
    const int h = b & 7;            // head -> XCD (round-robin assumption)
    const int chunk = b >> 3;       // 0..830
    const int t = threadIdx.x;
    const int rl = t >> 3;          // local row 0..31
    const int j = t & 7;            // lane within row (covers 8B of head slice)

    int row = chunk * 32 + rl;
    const bool valid = row < MTOT;
    if (row > MTOT - 1) row = MTOT - 1;
    const int frame = row >= LEN_Q ? 1 : 0;
    const int q = row - frame * LEN_Q;

    __shared__ float w_s[32][16][4];
    __shared__ int   idx_s[32][16][4];

    // ---- load off (2 lp per lane) + attn (2 vals per lane) for (row, h) ----
    uint2v ov = *(const uint2v*)(off + (size_t)row * 256 + h * 32 + j * 4);
    unsigned av = *(const unsigned*)(attn + (size_t)row * 128 + h * 16 + j * 2);
    float t0 = bf2f((unsigned short)(av & 0xffffu));
    float t1 = bf2f((unsigned short)(av >> 16));

    // ---- softmax over 16 values across the 8-lane row group ----
    float m = fmaxf(t0, t1);
    #pragma unroll
    for (int d = 1; d < 8; d <<= 1) m = fmaxf(m, __shfl_xor(m, d));
    float e0 = __expf(t0 - m);
    float e1 = __expf(t1 - m);
    float s = e0 + e1;
    #pragma unroll
    for (int d = 1; d < 8; d <<= 1) s += __shfl_xor(s, d);
    float inv = 1.f / s;
    float wt01[2] = { e0 * inv, e1 * inv };

    // ---- loc -> corner idx (byte) + weights; lane j owns lp = 2j, 2j+1 ----
    {
        const int l = j >> 1;                   // both lps share a level
        const int Hl = spatial[l * 2], Wl = spatial[l * 2 + 1];
        const int start = lsi[l];
        const float rx = refpts[((size_t)q * LEVELS + l) * 2];
        const float ry = refpts[((size_t)q * LEVELS + l) * 2 + 1];
        #pragma unroll
        for (int i = 0; i < 2; ++i) {
            const int lp = 2 * j + i;
            unsigned sel = (i == 0) ? ov.x : ov.y;
            float ox = bf2f((unsigned short)(sel & 0xffffu));
            float oy = bf2f((unsigned short)(sel >> 16));
            float locx = rx + ox * __builtin_amdgcn_rcpf((float)Wl);
            float locy = ry + oy * __builtin_amdgcn_rcpf((float)Hl);
            float wt = wt01[i];
            float x = locx * (float)Wl - 0.5f;
            float y = locy * (float)Hl - 0.5f;
            float x0f = floorf(x), y0f = floorf(y);
            float lx = x - x0f, ly = y - y0f;
            int x0 = (int)x0f, y0 = (int)y0f;
            int x1 = x0 + 1, y1 = y0 + 1;
            int vx0 = (x0 >= 0) & (x0 < Wl);
            int vx1 = (x1 >= 0) & (x1 < Wl);
            int vy0 = (y0 >= 0) & (y0 < Hl);
            int vy1 = (y1 >= 0) & (y1 < Hl);
            int x0c = min(max(x0, 0), Wl - 1);
            int x1c = min(max(x1, 0), Wl - 1);
            int y0c = min(max(y0, 0), Hl - 1);
            int y1c = min(max(y1, 0), Hl - 1);
            idx_s[rl][lp][0] = (start + y0c * Wl + x0c) * 512;
            idx_s[rl][lp][1] = (start + y0c * Wl + x1c) * 512;
            idx_s[rl][lp][2] = (start + y1c * Wl + x0c) * 512;
            idx_s[rl][lp][3] = (start + y1c * Wl + x1c) * 512;
            w_s[rl][lp][0] = (vy0 & vx0) ? wt * (1.f - lx) * (1.f - ly) : 0.f;
            w_s[rl][lp][1] = (vy0 & vx1) ? wt * lx * (1.f - ly) : 0.f;
            w_s[rl][lp][2] = (vy1 & vx0) ? wt * (1.f - lx) * ly : 0.f;
            w_s[rl][lp][3] = (vy1 & vx1) ? wt * lx * ly : 0.f;
        }
    }
    __syncthreads();

    // ---- double-buffered gather pipeline (groups of 8 samples) ----
    const char* vbase = (const char*)value + (size_t)frame * LEN_Q * 512 + h * 64 + j * 8;

    float  wbuf[2][8];
    uint2v vbuf[2][8];
    auto fetch = [&](int buf, int g) {
        #pragma unroll
        for (int jj = 0; jj < 8; ++jj) {
            int lp = 2 * g + (jj >> 2);
            int cr = jj & 3;
            wbuf[buf][jj] = w_s[rl][lp][cr];
            int idx = idx_s[rl][lp][cr];
            vbuf[buf][jj] = *(const uint2v*)(vbase + (size_t)idx);
        }
    };

    float a0 = 0.f, a1 = 0.f, a2 = 0.f, a3 = 0.f;
    fetch(0, 0);
    #pragma unroll
    for (int g = 0; g < 8; ++g) {
        const int cur = g & 1;
        if (g < 7) fetch(cur ^ 1, g + 1);   // issue next group's loads first
        #pragma unroll
        for (int jj = 0; jj < 8; ++jj) {
            float wc = wbuf[cur][jj];
            uint2v v = vbuf[cur][jj];
            a0 = fmaf(wc, __builtin_bit_cast(float, v.x << 16), a0);
            a1 = fmaf(wc, __builtin_bit_cast(float, v.x & 0xffff0000u), a1);
            a2 = fmaf(wc, __builtin_bit_cast(float, v.y << 16), a2);
            a3 = fmaf(wc, __builtin_bit_cast(float, v.y & 0xffff0000u), a3);
        }
    }
    if (valid) {
        ushort4v o;
        o.x = f2bf(a0); o.y = f2bf(a1); o.z = f2bf(a2); o.w = f2bf(a3);
        *(ushort4v*)(samp + (size_t)row * 256 + h * 32 + j * 4) = o;
    }
}

// ---------------------------------------------------------------------------
extern "C" void kernel_launch(void* const* d_in, const int* in_sizes, int n_in,
                              void* d_out, int out_size, void* d_ws, size_t ws_size,
                              hipStream_t stream)
{
    const float* query   = (const float*)d_in[0];
    const float* refpts  = (const float*)d_in[1];
    const float* inflat  = (const float*)d_in[2];
    const int*   spatial = (const int*)d_in[3];
    const int*   lsi     = (const int*)d_in[4];
    const float* Wv      = (const float*)d_in[5];
    const float* bv      = (const float*)d_in[6];
    const float* Woff    = (const float*)d_in[7];
    const float* boff    = (const float*)d_in[8];
    const float* Wattn   = (const float*)d_in[9];
    const float* battn   = (const float*)d_in[10];
    const float* Wout    = (const float*)d_in[11];
    const float* bout    = (const float*)d_in[12];

    unsigned short* ws = (unsigned short*)d_ws;
    const size_t MR = (size_t)MTOT * 256;
    unsigned short* v16    = ws;                        // MTOT*256
    unsigned short* off16  = v16 + MR;                  // MTOT*256
    unsigned short* at16   = off16 + MR;                // MTOT*128
    unsigned short* samp16 = at16 + (size_t)MTOT * 128; // MTOT*256
    unsigned short* wvT    = samp16 + MR;               // 256*256
    unsigned short* woaT   = wvT + 65536;               // 384*256
    unsigned short* woutT  = woaT + 98304;              // 256*256

    dim3 blk256(256);
    const int mBlocks = (MTOT + 127) / 128;             // 208

    hipLaunchKernelGGL(prep_weights, dim3(896), blk256, 0, stream,
                       Wv, Woff, Wattn, Wout, wvT, woaT, woutT);

    hipLaunchKernelGGL(gemm_fused, dim3(5, mBlocks), blk256, 0, stream,
                       inflat, query, wvT, woaT, bv, boff, battn,
                       v16, off16, at16, MTOT, 256);

    // 831 chunks of 32 rows per head, 8 heads -> 6648 blocks
    hipLaunchKernelGGL(sample8, dim3(6648), blk256, 0, stream,
                       v16, off16, at16, refpts, spatial, lsi, samp16);

    hipLaunchKernelGGL(gemm_out, dim3(2, mBlocks), blk256, 0, stream,
                       samp16, woutT, bout, (float*)d_out, MTOT, 256);
}

// Round 2
// 228.194 us; speedup vs baseline: 1.0142x; 1.0142x over previous
//
#include <hip/hip_runtime.h>
#include <math.h>

#define LEN_Q 13294
#define NFRAMES 2
#define MTOT (LEN_Q * NFRAMES)   // 26588
#define HEADS 8
#define LEVELS 4
#define POINTS 4

typedef __attribute__((ext_vector_type(8))) short short8;
typedef __attribute__((ext_vector_type(4))) float f32x4;
typedef __attribute__((ext_vector_type(4))) int i32x4;
typedef __attribute__((ext_vector_type(2))) unsigned int uint2v;
typedef __attribute__((ext_vector_type(4))) unsigned short ushort4v;

__device__ __forceinline__ unsigned short f2bf(float x) {
    unsigned u = __builtin_bit_cast(unsigned, x);
    unsigned r = (u + 0x7fffu + ((u >> 16) & 1u)) >> 16;
    return (unsigned short)r;
}
__device__ __forceinline__ float bf2f(unsigned short b) {
    return __builtin_bit_cast(float, (unsigned)b << 16);
}

#define LSTR 40   // LDS row stride (shorts) for the GEMMs

// ---------------------------------------------------------------------------
// prep: all 4 weight transposes f32[K,N] -> bf16[N,K] in one dispatch.
// ---------------------------------------------------------------------------
__global__ __launch_bounds__(256) void prep_weights(
    const float* __restrict__ Wv,  const float* __restrict__ Woff,
    const float* __restrict__ Wat, const float* __restrict__ Wout,
    unsigned short* __restrict__ wvT,   // 256x256
    unsigned short* __restrict__ woaT,  // 384x256
    unsigned short* __restrict__ woutT) // 256x256
{
    const int b = blockIdx.x;
    const int k = threadIdx.x;
    const float* src; unsigned short* dst; int N; int n;
    if (b < 256)      { src = Wv;   dst = wvT;          N = 256; n = b; }
    else if (b < 512) { src = Woff; dst = woaT;         N = 256; n = b - 256; }
    else if (b < 640) { src = Wat;  dst = woaT + 65536; N = 128; n = b - 512; }
    else              { src = Wout; dst = woutT;        N = 256; n = b - 640; }
    dst[(size_t)n * 256 + k] = f2bf(src[(size_t)k * N + n]);
}

// ---------------------------------------------------------------------------
// Fused GEMM (R9 register-prefetch version — kept, it won).
// ---------------------------------------------------------------------------
__global__ __launch_bounds__(256, 3) void gemm_fused(
    const float* __restrict__ Aval,
    const float* __restrict__ Aq,
    const unsigned short* __restrict__ BTv,   // [256,256]
    const unsigned short* __restrict__ BToa,  // [384,256]
    const float* __restrict__ bv,
    const float* __restrict__ boff,
    const float* __restrict__ battn,
    unsigned short* __restrict__ v16,
    unsigned short* __restrict__ off16,
    unsigned short* __restrict__ at16,
    int M, int K)
{
    __shared__ unsigned short As[128 * LSTR];
    __shared__ unsigned short Bs[128 * LSTR];

    const int t = threadIdx.x;
    const int w = t >> 6;
    const int L = t & 63;
    const int m0 = blockIdx.y * 128;
    const bool isVal = (blockIdx.x < 2);
    const int nTile = isVal ? blockIdx.x : blockIdx.x - 2;
    const float* Af = isVal ? Aval : Aq;
    const unsigned short* BTb = (isVal ? BTv : BToa) + (size_t)nTile * 128 * K;

    const int sr = t >> 1;
    const int sc = (t & 1) * 16;
    int arow = m0 + sr; if (arow > M - 1) arow = M - 1;
    const float* Ag = Af + (size_t)arow * K + sc;
    const unsigned short* Bg = BTb + (size_t)sr * K + sc;
    unsigned short* AsW = &As[sr * LSTR + sc];
    unsigned short* BsW = &Bs[sr * LSTR + sc];

    const int mq = (w & 1) * 64;
    const int nq = (w >> 1) * 64;
    const int lr = L & 15;
    const int kq = (L >> 4) * 8;

    f32x4 acc[4][4];
    #pragma unroll
    for (int i = 0; i < 4; ++i)
        #pragma unroll
        for (int j = 0; j < 4; ++j) acc[i][j] = (f32x4){0.f, 0.f, 0.f, 0.f};

    f32x4 a0 = *(const f32x4*)(Ag);
    f32x4 a1 = *(const f32x4*)(Ag + 4);
    f32x4 a2 = *(const f32x4*)(Ag + 8);
    f32x4 a3 = *(const f32x4*)(Ag + 12);
    short8 b0 = *(const short8*)(Bg);
    short8 b1 = *(const short8*)(Bg + 8);

    for (int k0 = 0; k0 < K; k0 += 32) {
        short8 p0, p1;
        p0[0]=(short)f2bf(a0.x); p0[1]=(short)f2bf(a0.y); p0[2]=(short)f2bf(a0.z); p0[3]=(short)f2bf(a0.w);
        p0[4]=(short)f2bf(a1.x); p0[5]=(short)f2bf(a1.y); p0[6]=(short)f2bf(a1.z); p0[7]=(short)f2bf(a1.w);
        p1[0]=(short)f2bf(a2.x); p1[1]=(short)f2bf(a2.y); p1[2]=(short)f2bf(a2.z); p1[3]=(short)f2bf(a2.w);
        p1[4]=(short)f2bf(a3.x); p1[5]=(short)f2bf(a3.y); p1[6]=(short)f2bf(a3.z); p1[7]=(short)f2bf(a3.w);
        __syncthreads();
        *(short8*)(AsW) = p0;
        *(short8*)(AsW + 8) = p1;
        *(short8*)(BsW) = b0;
        *(short8*)(BsW + 8) = b1;
        __syncthreads();

        if (k0 + 32 < K) {              // prefetch next tile (reg-private)
            a0 = *(const f32x4*)(Ag + k0 + 32);
            a1 = *(const f32x4*)(Ag + k0 + 36);
            a2 = *(const f32x4*)(Ag + k0 + 40);
            a3 = *(const f32x4*)(Ag + k0 + 44);
            b0 = *(const short8*)(Bg + k0 + 32);
            b1 = *(const short8*)(Bg + k0 + 40);
        }

        short8 af[4], bf[4];
        #pragma unroll
        for (int i = 0; i < 4; ++i)
            af[i] = *(const short8*)&As[(mq + i * 16 + lr) * LSTR + kq];
        #pragma unroll
        for (int j = 0; j < 4; ++j)
            bf[j] = *(const short8*)&Bs[(nq + j * 16 + lr) * LSTR + kq];
        #pragma unroll
        for (int i = 0; i < 4; ++i)
            #pragma unroll
            for (int j = 0; j < 4; ++j)
                acc[i][j] = __builtin_amdgcn_mfma_f32_16x16x32_bf16(af[i], bf[j], acc[i][j], 0, 0, 0);
    }

    const int rr = (L >> 4) * 4;
    #pragma unroll
    for (int i = 0; i < 4; ++i) {
        #pragma unroll
        for (int r = 0; r < 4; ++r) {
            int m = m0 + mq + i * 16 + rr + r;
            if (m < M) {
                #pragma unroll
                for (int j = 0; j < 4; ++j) {
                    int colg = nTile * 128 + nq + j * 16 + lr;
                    float v = acc[i][j][r];
                    if (isVal) {
                        v16[(size_t)m * 256 + colg] = f2bf(v + bv[colg]);
                    } else if (colg < 256) {
                        off16[(size_t)m * 256 + colg] = f2bf(v + boff[colg]);
                    } else {
                        at16[(size_t)m * 128 + (colg - 256)] = f2bf(v + battn[colg - 256]);
                    }
                }
            }
        }
    }
}

// ---------------------------------------------------------------------------
// Output GEMM (R9 register-prefetch version — kept).
// ---------------------------------------------------------------------------
__global__ __launch_bounds__(256, 3) void gemm_out(
    const unsigned short* __restrict__ A,
    const unsigned short* __restrict__ BT,
    const float* __restrict__ bias,
    float* __restrict__ C,
    int M, int K)
{
    __shared__ unsigned short As[128 * LSTR];
    __shared__ unsigned short Bs[128 * LSTR];

    const int t = threadIdx.x;
    const int w = t >> 6;
    const int L = t & 63;
    const int m0 = blockIdx.y * 128;
    const int n0 = blockIdx.x * 128;

    const int sr = t >> 1;
    const int sc = (t & 1) * 16;
    int arow = m0 + sr; if (arow > M - 1) arow = M - 1;
    const unsigned short* Ag = A + (size_t)arow * K + sc;
    const unsigned short* Bg = BT + (size_t)(n0 + sr) * K + sc;
    unsigned short* AsW = &As[sr * LSTR + sc];
    unsigned short* BsW = &Bs[sr * LSTR + sc];

    const int mq = (w & 1) * 64;
    const int nq = (w >> 1) * 64;
    const int lr = L & 15;
    const int kq = (L >> 4) * 8;

    f32x4 acc[4][4];
    #pragma unroll
    for (int i = 0; i < 4; ++i)
        #pragma unroll
        for (int j = 0; j < 4; ++j) acc[i][j] = (f32x4){0.f, 0.f, 0.f, 0.f};

    short8 a0 = *(const short8*)(Ag);
    short8 a1 = *(const short8*)(Ag + 8);
    short8 b0 = *(const short8*)(Bg);
    short8 b1 = *(const short8*)(Bg + 8);

    for (int k0 = 0; k0 < K; k0 += 32) {
        __syncthreads();
        *(short8*)(AsW) = a0;
        *(short8*)(AsW + 8) = a1;
        *(short8*)(BsW) = b0;
        *(short8*)(BsW + 8) = b1;
        __syncthreads();

        if (k0 + 32 < K) {
            a0 = *(const short8*)(Ag + k0 + 32);
            a1 = *(const short8*)(Ag + k0 + 40);
            b0 = *(const short8*)(Bg + k0 + 32);
            b1 = *(const short8*)(Bg + k0 + 40);
        }

        short8 af[4], bf[4];
        #pragma unroll
        for (int i = 0; i < 4; ++i)
            af[i] = *(const short8*)&As[(mq + i * 16 + lr) * LSTR + kq];
        #pragma unroll
        for (int j = 0; j < 4; ++j)
            bf[j] = *(const short8*)&Bs[(nq + j * 16 + lr) * LSTR + kq];
        #pragma unroll
        for (int i = 0; i < 4; ++i)
            #pragma unroll
            for (int j = 0; j < 4; ++j)
                acc[i][j] = __builtin_amdgcn_mfma_f32_16x16x32_bf16(af[i], bf[j], acc[i][j], 0, 0, 0);
    }

    const int rr = (L >> 4) * 4;
    #pragma unroll
    for (int i = 0; i < 4; ++i) {
        #pragma unroll
        for (int r = 0; r < 4; ++r) {
            int m = m0 + mq + i * 16 + rr + r;
            if (m < M) {
                #pragma unroll
                for (int j = 0; j < 4; ++j) {
                    int n = n0 + nq + j * 16 + lr;
                    C[(size_t)m * 256 + n] = acc[i][j][r] + bias[n];
                }
            }
        }
    }
}

// ---------------------------------------------------------------------------
// Sampler v9: sample8 structure + LDS bank-conflict fix.
//   - w_s/idx_s padded to 68-word row stride: start bank = rl*4 + const ->
//     8 distinct banks across the wave's 8 row-groups (was 8-way conflict:
//     stride 64 words put every rl in bank 0 -> SQ_LDS_BANK_CONFLICT 1.23e7,
//     ~28% of all cycles).
//   - LDS reads vectorized: ds_read_b128 per (lp) for weights and indices
//     (32 reads/lane instead of 128 conflicted b32 reads).
//   - frame/head byte offsets folded into stored idx -> gather address is
//     value + u32(idx + j*8) (saddr-form global_load, 1 v_add per load).
//   FMA order per accumulator bit-identical to sample8.
// ---------------------------------------------------------------------------
__global__ __launch_bounds__(256) void sample9(
    const unsigned short* __restrict__ value,  // bf16 [MTOT,256]
    const unsigned short* __restrict__ off,    // bf16 [MTOT,256]
    const unsigned short* __restrict__ attn,   // bf16 [MTOT,128]
    const float* __restrict__ refpts,          // [LEN_Q, LEVELS, 2]
    const int*   __restrict__ spatial,         // [LEVELS,2] (H,W)
    const int*   __restrict__ lsi,             // [LEVELS]
    unsigned short* __restrict__ samp)         // bf16 [MTOT,256]
{
    const int b = blockIdx.x;
    const int h = b & 7;            // head -> XCD (round-robin assumption)
    const int chunk = b >> 3;       // 0..830
    const int t = threadIdx.x;
    const int rl = t >> 3;          // local row 0..31
    const int j = t & 7;            // lane within row (covers 8B of head slice)

    int row = chunk * 32 + rl;
    const bool valid = row < MTOT;
    if (row > MTOT - 1) row = MTOT - 1;
    const int frame = row >= LEN_Q ? 1 : 0;
    const int q = row - frame * LEN_Q;

    __shared__ float w_s[32][68];   // [rl][lp*4+cr], padded stride (68 words)
    __shared__ int   idx_s[32][68];

    // ---- load off (2 lp per lane) + attn (2 vals per lane) for (row, h) ----
    uint2v ov = *(const uint2v*)(off + (size_t)row * 256 + h * 32 + j * 4);
    unsigned av = *(const unsigned*)(attn + (size_t)row * 128 + h * 16 + j * 2);
    float t0 = bf2f((unsigned short)(av & 0xffffu));
    float t1 = bf2f((unsigned short)(av >> 16));

    // ---- softmax over 16 values across the 8-lane row group ----
    float m = fmaxf(t0, t1);
    #pragma unroll
    for (int d = 1; d < 8; d <<= 1) m = fmaxf(m, __shfl_xor(m, d));
    float e0 = __expf(t0 - m);
    float e1 = __expf(t1 - m);
    float s = e0 + e1;
    #pragma unroll
    for (int d = 1; d < 8; d <<= 1) s += __shfl_xor(s, d);
    float inv = 1.f / s;
    float wt01[2] = { e0 * inv, e1 * inv };

    // ---- loc -> corner byte-idx (with frame/head folded in) + weights ----
    {
        const int l = j >> 1;                   // both lps share a level
        const int Hl = spatial[l * 2], Wl = spatial[l * 2 + 1];
        const int start = lsi[l];
        const int voff0 = frame * (LEN_Q * 512) + h * 64;
        const float rx = refpts[((size_t)q * LEVELS + l) * 2];
        const float ry = refpts[((size_t)q * LEVELS + l) * 2 + 1];
        #pragma unroll
        for (int i = 0; i < 2; ++i) {
            const int lp = 2 * j + i;
            unsigned sel = (i == 0) ? ov.x : ov.y;
            float ox = bf2f((unsigned short)(sel & 0xffffu));
            float oy = bf2f((unsigned short)(sel >> 16));
            float locx = rx + ox * __builtin_amdgcn_rcpf((float)Wl);
            float locy = ry + oy * __builtin_amdgcn_rcpf((float)Hl);
            float wt = wt01[i];
            float x = locx * (float)Wl - 0.5f;
            float y = locy * (float)Hl - 0.5f;
            float x0f = floorf(x), y0f = floorf(y);
            float lx = x - x0f, ly = y - y0f;
            int x0 = (int)x0f, y0 = (int)y0f;
            int x1 = x0 + 1, y1 = y0 + 1;
            int vx0 = (x0 >= 0) & (x0 < Wl);
            int vx1 = (x1 >= 0) & (x1 < Wl);
            int vy0 = (y0 >= 0) & (y0 < Hl);
            int vy1 = (y1 >= 0) & (y1 < Hl);
            int x0c = min(max(x0, 0), Wl - 1);
            int x1c = min(max(x1, 0), Wl - 1);
            int y0c = min(max(y0, 0), Hl - 1);
            int y1c = min(max(y1, 0), Hl - 1);
            i32x4 iv;
            iv.x = voff0 + (start + y0c * Wl + x0c) * 512;
            iv.y = voff0 + (start + y0c * Wl + x1c) * 512;
            iv.z = voff0 + (start + y1c * Wl + x0c) * 512;
            iv.w = voff0 + (start + y1c * Wl + x1c) * 512;
            f32x4 wv;
            wv.x = (vy0 & vx0) ? wt * (1.f - lx) * (1.f - ly) : 0.f;
            wv.y = (vy0 & vx1) ? wt * lx * (1.f - ly) : 0.f;
            wv.z = (vy1 & vx0) ? wt * (1.f - lx) * ly : 0.f;
            wv.w = (vy1 & vx1) ? wt * lx * ly : 0.f;
            *(i32x4*)&idx_s[rl][lp * 4] = iv;   // 16B aligned (272*rl + 16*lp)
            *(f32x4*)&w_s[rl][lp * 4] = wv;
        }
    }
    __syncthreads();

    // ---- double-buffered gather pipeline (groups of 8 samples = 2 lp) ----
    const char* vb = (const char*)value;
    const unsigned lane8 = (unsigned)(j * 8);

    f32x4  wreg[2][2];
    uint2v vbuf[2][8];
    auto fetch = [&](int buf, int g) {
        wreg[buf][0] = *(const f32x4*)&w_s[rl][(2 * g) * 4];
        wreg[buf][1] = *(const f32x4*)&w_s[rl][(2 * g + 1) * 4];
        i32x4 i0 = *(const i32x4*)&idx_s[rl][(2 * g) * 4];
        i32x4 i1 = *(const i32x4*)&idx_s[rl][(2 * g + 1) * 4];
        vbuf[buf][0] = *(const uint2v*)(vb + (unsigned)(i0.x) + lane8);
        vbuf[buf][1] = *(const uint2v*)(vb + (unsigned)(i0.y) + lane8);
        vbuf[buf][2] = *(const uint2v*)(vb + (unsigned)(i0.z) + lane8);
        vbuf[buf][3] = *(const uint2v*)(vb + (unsigned)(i0.w) + lane8);
        vbuf[buf][4] = *(const uint2v*)(vb + (unsigned)(i1.x) + lane8);
        vbuf[buf][5] = *(const uint2v*)(vb + (unsigned)(i1.y) + lane8);
        vbuf[buf][6] = *(const uint2v*)(vb + (unsigned)(i1.z) + lane8);
        vbuf[buf][7] = *(const uint2v*)(vb + (unsigned)(i1.w) + lane8);
    };

    float a0 = 0.f, a1 = 0.f, a2 = 0.f, a3 = 0.f;
    fetch(0, 0);
    #pragma unroll
    for (int g = 0; g < 8; ++g) {
        const int cur = g & 1;
        if (g < 7) fetch(cur ^ 1, g + 1);   // issue next group's loads first
        #pragma unroll
        for (int p = 0; p < 2; ++p) {
            f32x4 wv = wreg[cur][p];
            #pragma unroll
            for (int c = 0; c < 4; ++c) {
                float wc = wv[c];
                uint2v v = vbuf[cur][p * 4 + c];
                a0 = fmaf(wc, __builtin_bit_cast(float, v.x << 16), a0);
                a1 = fmaf(wc, __builtin_bit_cast(float, v.x & 0xffff0000u), a1);
                a2 = fmaf(wc, __builtin_bit_cast(float, v.y << 16), a2);
                a3 = fmaf(wc, __builtin_bit_cast(float, v.y & 0xffff0000u), a3);
            }
        }
    }
    if (valid) {
        ushort4v o;
        o.x = f2bf(a0); o.y = f2bf(a1); o.z = f2bf(a2); o.w = f2bf(a3);
        *(ushort4v*)(samp + (size_t)row * 256 + h * 32 + j * 4) = o;
    }
}

// ---------------------------------------------------------------------------
extern "C" void kernel_launch(void* const* d_in, const int* in_sizes, int n_in,
                              void* d_out, int out_size, void* d_ws, size_t ws_size,
                              hipStream_t stream)
{
    const float* query   = (const float*)d_in[0];
    const float* refpts  = (const float*)d_in[1];
    const float* inflat  = (const float*)d_in[2];
    const int*   spatial = (const int*)d_in[3];
    const int*   lsi     = (const int*)d_in[4];
    const float* Wv      = (const float*)d_in[5];
    const float* bv      = (const float*)d_in[6];
    const float* Woff    = (const float*)d_in[7];
    const float* boff    = (const float*)d_in[8];
    const float* Wattn   = (const float*)d_in[9];
    const float* battn   = (const float*)d_in[10];
    const float* Wout    = (const float*)d_in[11];
    const float* bout    = (const float*)d_in[12];

    unsigned short* ws = (unsigned short*)d_ws;
    const size_t MR = (size_t)MTOT * 256;
    unsigned short* v16    = ws;                        // MTOT*256
    unsigned short* off16  = v16 + MR;                  // MTOT*256
    unsigned short* at16   = off16 + MR;                // MTOT*128
    unsigned short* samp16 = at16 + (size_t)MTOT * 128; // MTOT*256
    unsigned short* wvT    = samp16 + MR;               // 256*256
    unsigned short* woaT   = wvT + 65536;               // 384*256
    unsigned short* woutT  = woaT + 98304;              // 256*256

    dim3 blk256(256);
    const int mBlocks = (MTOT + 127) / 128;             // 208

    hipLaunchKernelGGL(prep_weights, dim3(896), blk256, 0, stream,
                       Wv, Woff, Wattn, Wout, wvT, woaT, woutT);

    hipLaunchKernelGGL(gemm_fused, dim3(5, mBlocks), blk256, 0, stream,
                       inflat, query, wvT, woaT, bv, boff, battn,
                       v16, off16, at16, MTOT, 256);

    // 831 chunks of 32 rows per head, 8 heads -> 6648 blocks
    hipLaunchKernelGGL(sample9, dim3(6648), blk256, 0, stream,
                       v16, off16, at16, refpts, spatial, lsi, samp16);

    hipLaunchKernelGGL(gemm_out, dim3(2, mBlocks), blk256, 0, stream,
                       samp16, woutT, bout, (float*)d_out, MTOT, 256);
}

// Round 4
// 207.165 us; speedup vs baseline: 1.1171x; 1.1015x over previous
//
#include <hip/hip_runtime.h>
#include <math.h>

#define LEN_Q 13294
#define LEN_IN 13294
#define NFRAMES 2
#define MTOT (LEN_Q * NFRAMES)   // 26588
#define HEADS 8
#define LEVELS 4
#define POINTS 4

typedef __attribute__((ext_vector_type(8))) short short8;
typedef __attribute__((ext_vector_type(4))) float f32x4;
typedef __attribute__((ext_vector_type(4))) int i32x4;
typedef __attribute__((ext_vector_type(2))) unsigned int uint2v;
typedef __attribute__((ext_vector_type(4))) unsigned int uint4v;
typedef __attribute__((ext_vector_type(4))) unsigned short ushort4v;

__device__ __forceinline__ unsigned short f2bf(float x) {
    unsigned u = __builtin_bit_cast(unsigned, x);
    unsigned r = (u + 0x7fffu + ((u >> 16) & 1u)) >> 16;
    return (unsigned short)r;
}
__device__ __forceinline__ float bf2f(unsigned short b) {
    return __builtin_bit_cast(float, (unsigned)b << 16);
}
__device__ __forceinline__ float bfl(unsigned u) {
    return __builtin_bit_cast(float, u << 16);
}
__device__ __forceinline__ float bfh(unsigned u) {
    return __builtin_bit_cast(float, u & 0xffff0000u);
}

#define LSTR 40   // LDS row stride (shorts) for the GEMMs

// ---------------------------------------------------------------------------
// prep: all 4 weight transposes f32[K,N] -> bf16[N,K] in one dispatch.
// ---------------------------------------------------------------------------
__global__ __launch_bounds__(256) void prep_weights(
    const float* __restrict__ Wv,  const float* __restrict__ Woff,
    const float* __restrict__ Wat, const float* __restrict__ Wout,
    unsigned short* __restrict__ wvT,   // 256x256
    unsigned short* __restrict__ woaT,  // 384x256
    unsigned short* __restrict__ woutT) // 256x256
{
    const int b = blockIdx.x;
    const int k = threadIdx.x;
    const float* src; unsigned short* dst; int N; int n;
    if (b < 256)      { src = Wv;   dst = wvT;          N = 256; n = b; }
    else if (b < 512) { src = Woff; dst = woaT;         N = 256; n = b - 256; }
    else if (b < 640) { src = Wat;  dst = woaT + 65536; N = 128; n = b - 512; }
    else              { src = Wout; dst = woutT;        N = 256; n = b - 640; }
    dst[(size_t)n * 256 + k] = f2bf(src[(size_t)k * N + n]);
}

// ---------------------------------------------------------------------------
// Fused GEMM. Value outputs go to the pair-duplicated head-major table:
//   vdup[frame][head][entry] = 128B: value[entry] (lo 64B) || value[entry+1]
//   (hi 64B, written when processing entry+1). Pitch LEN_IN+1 entries.
// ---------------------------------------------------------------------------
__global__ __launch_bounds__(256, 3) void gemm_fused(
    const float* __restrict__ Aval,
    const float* __restrict__ Aq,
    const unsigned short* __restrict__ BTv,   // [256,256]
    const unsigned short* __restrict__ BToa,  // [384,256]
    const float* __restrict__ bv,
    const float* __restrict__ boff,
    const float* __restrict__ battn,
    unsigned short* __restrict__ vdup,
    unsigned short* __restrict__ off16,
    unsigned short* __restrict__ at16,
    int M, int K)
{
    __shared__ unsigned short As[128 * LSTR];
    __shared__ unsigned short Bs[128 * LSTR];

    const int t = threadIdx.x;
    const int w = t >> 6;
    const int L = t & 63;
    const int m0 = blockIdx.y * 128;
    const bool isVal = (blockIdx.x < 2);
    const int nTile = isVal ? blockIdx.x : blockIdx.x - 2;
    const float* Af = isVal ? Aval : Aq;
    const unsigned short* BTb = (isVal ? BTv : BToa) + (size_t)nTile * 128 * K;

    const int sr = t >> 1;
    const int sc = (t & 1) * 16;
    int arow = m0 + sr; if (arow > M - 1) arow = M - 1;
    const float* Ag = Af + (size_t)arow * K + sc;
    const unsigned short* Bg = BTb + (size_t)sr * K + sc;
    unsigned short* AsW = &As[sr * LSTR + sc];
    unsigned short* BsW = &Bs[sr * LSTR + sc];

    const int mq = (w & 1) * 64;
    const int nq = (w >> 1) * 64;
    const int lr = L & 15;
    const int kq = (L >> 4) * 8;

    f32x4 acc[4][4];
    #pragma unroll
    for (int i = 0; i < 4; ++i)
        #pragma unroll
        for (int j = 0; j < 4; ++j) acc[i][j] = (f32x4){0.f, 0.f, 0.f, 0.f};

    f32x4 a0 = *(const f32x4*)(Ag);
    f32x4 a1 = *(const f32x4*)(Ag + 4);
    f32x4 a2 = *(const f32x4*)(Ag + 8);
    f32x4 a3 = *(const f32x4*)(Ag + 12);
    short8 b0 = *(const short8*)(Bg);
    short8 b1 = *(const short8*)(Bg + 8);

    for (int k0 = 0; k0 < K; k0 += 32) {
        short8 p0, p1;
        p0[0]=(short)f2bf(a0.x); p0[1]=(short)f2bf(a0.y); p0[2]=(short)f2bf(a0.z); p0[3]=(short)f2bf(a0.w);
        p0[4]=(short)f2bf(a1.x); p0[5]=(short)f2bf(a1.y); p0[6]=(short)f2bf(a1.z); p0[7]=(short)f2bf(a1.w);
        p1[0]=(short)f2bf(a2.x); p1[1]=(short)f2bf(a2.y); p1[2]=(short)f2bf(a2.z); p1[3]=(short)f2bf(a2.w);
        p1[4]=(short)f2bf(a3.x); p1[5]=(short)f2bf(a3.y); p1[6]=(short)f2bf(a3.z); p1[7]=(short)f2bf(a3.w);
        __syncthreads();
        *(short8*)(AsW) = p0;
        *(short8*)(AsW + 8) = p1;
        *(short8*)(BsW) = b0;
        *(short8*)(BsW + 8) = b1;
        __syncthreads();

        if (k0 + 32 < K) {              // prefetch next tile (reg-private)
            a0 = *(const f32x4*)(Ag + k0 + 32);
            a1 = *(const f32x4*)(Ag + k0 + 36);
            a2 = *(const f32x4*)(Ag + k0 + 40);
            a3 = *(const f32x4*)(Ag + k0 + 44);
            b0 = *(const short8*)(Bg + k0 + 32);
            b1 = *(const short8*)(Bg + k0 + 40);
        }

        short8 af[4], bf[4];
        #pragma unroll
        for (int i = 0; i < 4; ++i)
            af[i] = *(const short8*)&As[(mq + i * 16 + lr) * LSTR + kq];
        #pragma unroll
        for (int j = 0; j < 4; ++j)
            bf[j] = *(const short8*)&Bs[(nq + j * 16 + lr) * LSTR + kq];
        #pragma unroll
        for (int i = 0; i < 4; ++i)
            #pragma unroll
            for (int j = 0; j < 4; ++j)
                acc[i][j] = __builtin_amdgcn_mfma_f32_16x16x32_bf16(af[i], bf[j], acc[i][j], 0, 0, 0);
    }

    const int rr = (L >> 4) * 4;
    #pragma unroll
    for (int i = 0; i < 4; ++i) {
        #pragma unroll
        for (int r = 0; r < 4; ++r) {
            int m = m0 + mq + i * 16 + rr + r;
            if (m < M) {
                #pragma unroll
                for (int j = 0; j < 4; ++j) {
                    int colg = nTile * 128 + nq + j * 16 + lr;
                    float v = acc[i][j][r];
                    if (isVal) {
                        int hh = colg >> 5, d = colg & 31;
                        int fr = (m >= LEN_Q) ? 1 : 0;
                        int e = m - fr * LEN_Q;
                        size_t ebase = ((size_t)(fr * 8 + hh) * (LEN_IN + 1) + e) * 64;
                        unsigned short bvv = f2bf(v + bv[colg]);
                        vdup[ebase + d] = bvv;                       // lo half of entry e
                        if (e > 0) vdup[ebase - 64 + 32 + d] = bvv;  // hi half of entry e-1
                    } else if (colg < 256) {
                        off16[(size_t)m * 256 + colg] = f2bf(v + boff[colg]);
                    } else {
                        at16[(size_t)m * 128 + (colg - 256)] = f2bf(v + battn[colg - 256]);
                    }
                }
            }
        }
    }
}

// ---------------------------------------------------------------------------
// Output GEMM (R9 register-prefetch version — kept).
// ---------------------------------------------------------------------------
__global__ __launch_bounds__(256, 3) void gemm_out(
    const unsigned short* __restrict__ A,
    const unsigned short* __restrict__ BT,
    const float* __restrict__ bias,
    float* __restrict__ C,
    int M, int K)
{
    __shared__ unsigned short As[128 * LSTR];
    __shared__ unsigned short Bs[128 * LSTR];

    const int t = threadIdx.x;
    const int w = t >> 6;
    const int L = t & 63;
    const int m0 = blockIdx.y * 128;
    const int n0 = blockIdx.x * 128;

    const int sr = t >> 1;
    const int sc = (t & 1) * 16;
    int arow = m0 + sr; if (arow > M - 1) arow = M - 1;
    const unsigned short* Ag = A + (size_t)arow * K + sc;
    const unsigned short* Bg = BT + (size_t)(n0 + sr) * K + sc;
    unsigned short* AsW = &As[sr * LSTR + sc];
    unsigned short* BsW = &Bs[sr * LSTR + sc];

    const int mq = (w & 1) * 64;
    const int nq = (w >> 1) * 64;
    const int lr = L & 15;
    const int kq = (L >> 4) * 8;

    f32x4 acc[4][4];
    #pragma unroll
    for (int i = 0; i < 4; ++i)
        #pragma unroll
        for (int j = 0; j < 4; ++j) acc[i][j] = (f32x4){0.f, 0.f, 0.f, 0.f};

    short8 a0 = *(const short8*)(Ag);
    short8 a1 = *(const short8*)(Ag + 8);
    short8 b0 = *(const short8*)(Bg);
    short8 b1 = *(const short8*)(Bg + 8);

    for (int k0 = 0; k0 < K; k0 += 32) {
        __syncthreads();
        *(short8*)(AsW) = a0;
        *(short8*)(AsW + 8) = a1;
        *(short8*)(BsW) = b0;
        *(short8*)(BsW + 8) = b1;
        __syncthreads();

        if (k0 + 32 < K) {
            a0 = *(const short8*)(Ag + k0 + 32);
            a1 = *(const short8*)(Ag + k0 + 40);
            b0 = *(const short8*)(Bg + k0 + 32);
            b1 = *(const short8*)(Bg + k0 + 40);
        }

        short8 af[4], bf[4];
        #pragma unroll
        for (int i = 0; i < 4; ++i)
            af[i] = *(const short8*)&As[(mq + i * 16 + lr) * LSTR + kq];
        #pragma unroll
        for (int j = 0; j < 4; ++j)
            bf[j] = *(const short8*)&Bs[(nq + j * 16 + lr) * LSTR + kq];
        #pragma unroll
        for (int i = 0; i < 4; ++i)
            #pragma unroll
            for (int j = 0; j < 4; ++j)
                acc[i][j] = __builtin_amdgcn_mfma_f32_16x16x32_bf16(af[i], bf[j], acc[i][j], 0, 0, 0);
    }

    const int rr = (L >> 4) * 4;
    #pragma unroll
    for (int i = 0; i < 4; ++i) {
        #pragma unroll
        for (int r = 0; r < 4; ++r) {
            int m = m0 + mq + i * 16 + rr + r;
            if (m < M) {
                #pragma unroll
                for (int j = 0; j < 4; ++j) {
                    int n = n0 + nq + j * 16 + lr;
                    C[(size_t)m * 256 + n] = acc[i][j][r] + bias[n];
                }
            }
        }
    }
}

// ---------------------------------------------------------------------------
// Sampler v10: full-line gathers via the pair-duplicated head-major table.
//   Per (lp, y-corner): ONE 128B-aligned load (both x-corners) instead of two
//   scattered 64B half-line loads -> line traffic and request count halve.
//   Edge clamping via base-shift: xbase=clamp(x0,0,W-2), ybase=clamp(y0,0,H-2)
//   with weights remapped to the (e0,e1)x(r0,r1) slots (invalid corners -> 0).
//   Lanes 0-3 consume lo corner, 4-7 hi corner (8 dims each); one
//   __shfl_xor(.,4) merges the partials.
// ---------------------------------------------------------------------------
__global__ __launch_bounds__(256) void sample10(
    const unsigned short* __restrict__ vdup,   // bf16 [16][LEN_IN+1][64]
    const unsigned short* __restrict__ off,    // bf16 [MTOT,256]
    const unsigned short* __restrict__ attn,   // bf16 [MTOT,128]
    const float* __restrict__ refpts,          // [LEN_Q, LEVELS, 2]
    const int*   __restrict__ spatial,         // [LEVELS,2] (H,W)
    const int*   __restrict__ lsi,             // [LEVELS]
    unsigned short* __restrict__ samp)         // bf16 [MTOT,256]
{
    const int b = blockIdx.x;
    const int h = b & 7;            // head -> XCD (round-robin)
    const int chunk = b >> 3;       // 0..830
    const int t = threadIdx.x;
    const int rl = t >> 3;          // local row 0..31
    const int j = t & 7;            // lane within row

    int row = chunk * 32 + rl;
    const bool valid = row < MTOT;
    if (row > MTOT - 1) row = MTOT - 1;
    const int frame = row >= LEN_Q ? 1 : 0;
    const int q = row - frame * LEN_Q;

    __shared__ float w_s[32][68];   // 4 slot-weights per lp (padded stride)
    __shared__ int   b_s[32][20];   // pair-base byte offset per lp

    // ---- load off (2 lp per lane) + attn (2 vals per lane) for (row, h) ----
    uint2v ov = *(const uint2v*)(off + (size_t)row * 256 + h * 32 + j * 4);
    unsigned av = *(const unsigned*)(attn + (size_t)row * 128 + h * 16 + j * 2);
    float t0 = bf2f((unsigned short)(av & 0xffffu));
    float t1 = bf2f((unsigned short)(av >> 16));

    // ---- softmax over 16 values across the 8-lane row group ----
    float m = fmaxf(t0, t1);
    #pragma unroll
    for (int d = 1; d < 8; d <<= 1) m = fmaxf(m, __shfl_xor(m, d));
    float e0 = __expf(t0 - m);
    float e1 = __expf(t1 - m);
    float s = e0 + e1;
    #pragma unroll
    for (int d = 1; d < 8; d <<= 1) s += __shfl_xor(s, d);
    float inv = 1.f / s;
    float wt01[2] = { e0 * inv, e1 * inv };

    // ---- loc -> pair base + 4 slot weights ----
    {
        const int l = j >> 1;                   // both lps share a level
        const int Hl = spatial[l * 2], Wl = spatial[l * 2 + 1];
        const int start = lsi[l];
        const int slab = (frame * 8 + h) * (LEN_IN + 1);
        const float rx = refpts[((size_t)q * LEVELS + l) * 2];
        const float ry = refpts[((size_t)q * LEVELS + l) * 2 + 1];
        #pragma unroll
        for (int i = 0; i < 2; ++i) {
            const int lp = 2 * j + i;
            unsigned sel = (i == 0) ? ov.x : ov.y;
            float ox = bf2f((unsigned short)(sel & 0xffffu));
            float oy = bf2f((unsigned short)(sel >> 16));
            float locx = rx + ox * __builtin_amdgcn_rcpf((float)Wl);
            float locy = ry + oy * __builtin_amdgcn_rcpf((float)Hl);
            float wt = wt01[i];
            float x = locx * (float)Wl - 0.5f;
            float y = locy * (float)Hl - 0.5f;
            float x0f = floorf(x), y0f = floorf(y);
            float lx = x - x0f, ly = y - y0f;
            int x0 = (int)x0f, y0 = (int)y0f;
            int xbase = min(max(x0, 0), Wl - 2);
            int ybase = min(max(y0, 0), Hl - 2);
            // slot weights along x: e0 = xbase, e1 = xbase+1
            float wxe0 = (x0 == xbase) ? (1.f - lx) : ((x0 == -1) ? lx : 0.f);
            float wxe1 = (x0 == xbase) ? lx : ((x0 == Wl - 1) ? (1.f - lx) : 0.f);
            // slot weights along y: r0 = ybase, r1 = ybase+1
            float wye0 = (y0 == ybase) ? (1.f - ly) : ((y0 == -1) ? ly : 0.f);
            float wye1 = (y0 == ybase) ? ly : ((y0 == Hl - 1) ? (1.f - ly) : 0.f);
            b_s[rl][lp] = (slab + start + ybase * Wl + xbase) * 128;
            f32x4 wv;
            wv.x = wt * wxe0 * wye0;   // (r0, e0) -> lo half, y0-row pair
            wv.y = wt * wxe1 * wye0;   // (r0, e1) -> hi half
            wv.z = wt * wxe0 * wye1;   // (r1, e0)
            wv.w = wt * wxe1 * wye1;   // (r1, e1)
            *(f32x4*)&w_s[rl][lp * 4] = wv;
        }
    }
    __syncthreads();

    // ---- double-buffered pair-gather pipeline (2 lp per group) ----
    const char* vb = (const char*)vdup;
    const unsigned lane16 = (unsigned)(j * 16);
    const int hi = (j >> 2) & 1;                 // 0: lo corner, 1: hi corner
    int ystr[4];
    #pragma unroll
    for (int l2 = 0; l2 < 4; ++l2) ystr[l2] = spatial[l2 * 2 + 1] * 128;

    f32x4  wreg[2][2];
    uint4v vbuf[2][4];
    auto fetch = [&](int buf, int g) {
        wreg[buf][0] = *(const f32x4*)&w_s[rl][(2 * g) * 4];
        wreg[buf][1] = *(const f32x4*)&w_s[rl][(2 * g + 1) * 4];
        int b0 = b_s[rl][2 * g];
        int b1 = b_s[rl][2 * g + 1];
        int ys = ystr[g >> 1];
        vbuf[buf][0] = *(const uint4v*)(vb + (unsigned)b0 + lane16);
        vbuf[buf][1] = *(const uint4v*)(vb + (unsigned)(b0 + ys) + lane16);
        vbuf[buf][2] = *(const uint4v*)(vb + (unsigned)b1 + lane16);
        vbuf[buf][3] = *(const uint4v*)(vb + (unsigned)(b1 + ys) + lane16);
    };

    float a[8];
    #pragma unroll
    for (int k = 0; k < 8; ++k) a[k] = 0.f;

    fetch(0, 0);
    #pragma unroll
    for (int g = 0; g < 8; ++g) {
        const int cur = g & 1;
        if (g < 7) fetch(cur ^ 1, g + 1);   // issue next group's loads first
        #pragma unroll
        for (int p = 0; p < 2; ++p) {
            f32x4 w4 = wreg[cur][p];
            float wy0 = hi ? w4.y : w4.x;
            float wy1 = hi ? w4.w : w4.z;
            uint4v v0 = vbuf[cur][p * 2];
            uint4v v1 = vbuf[cur][p * 2 + 1];
            #pragma unroll
            for (int k = 0; k < 4; ++k) {
                unsigned u0 = v0[k], u1 = v1[k];
                a[2 * k]     = fmaf(wy0, bfl(u0), a[2 * k]);
                a[2 * k + 1] = fmaf(wy0, bfh(u0), a[2 * k + 1]);
                a[2 * k]     = fmaf(wy1, bfl(u1), a[2 * k]);
                a[2 * k + 1] = fmaf(wy1, bfh(u1), a[2 * k + 1]);
            }
        }
    }

    // merge lo/hi corner partials across the j / j+4 lane pair
    #pragma unroll
    for (int k = 0; k < 8; ++k) a[k] += __shfl_xor(a[k], 4);

    if (valid && hi == 0) {
        uint4v o;
        #pragma unroll
        for (int k = 0; k < 4; ++k)
            o[k] = (unsigned)f2bf(a[2 * k]) | ((unsigned)f2bf(a[2 * k + 1]) << 16);
        // dims d0 = (j&3)*8 .. +8 of this row's head slice
        *(uint4v*)(samp + (size_t)row * 256 + h * 32 + (j & 3) * 8) = o;
    }
}

// ---------------------------------------------------------------------------
extern "C" void kernel_launch(void* const* d_in, const int* in_sizes, int n_in,
                              void* d_out, int out_size, void* d_ws, size_t ws_size,
                              hipStream_t stream)
{
    const float* query   = (const float*)d_in[0];
    const float* refpts  = (const float*)d_in[1];
    const float* inflat  = (const float*)d_in[2];
    const int*   spatial = (const int*)d_in[3];
    const int*   lsi     = (const int*)d_in[4];
    const float* Wv      = (const float*)d_in[5];
    const float* bv      = (const float*)d_in[6];
    const float* Woff    = (const float*)d_in[7];
    const float* boff    = (const float*)d_in[8];
    const float* Wattn   = (const float*)d_in[9];
    const float* battn   = (const float*)d_in[10];
    const float* Wout    = (const float*)d_in[11];
    const float* bout    = (const float*)d_in[12];

    unsigned short* ws = (unsigned short*)d_ws;
    const size_t MR = (size_t)MTOT * 256;
    const size_t VDUP = (size_t)16 * (LEN_IN + 1) * 64;  // 13,614,080 shorts
    unsigned short* vdup   = ws;
    unsigned short* off16  = vdup + VDUP;               // MTOT*256
    unsigned short* at16   = off16 + MR;                // MTOT*128
    unsigned short* samp16 = at16 + (size_t)MTOT * 128; // MTOT*256
    unsigned short* wvT    = samp16 + MR;               // 256*256
    unsigned short* woaT   = wvT + 65536;               // 384*256
    unsigned short* woutT  = woaT + 98304;              // 256*256

    dim3 blk256(256);
    const int mBlocks = (MTOT + 127) / 128;             // 208

    hipLaunchKernelGGL(prep_weights, dim3(896), blk256, 0, stream,
                       Wv, Woff, Wattn, Wout, wvT, woaT, woutT);

    hipLaunchKernelGGL(gemm_fused, dim3(5, mBlocks), blk256, 0, stream,
                       inflat, query, wvT, woaT, bv, boff, battn,
                       vdup, off16, at16, MTOT, 256);

    // 831 chunks of 32 rows per head, 8 heads -> 6648 blocks
    hipLaunchKernelGGL(sample10, dim3(6648), blk256, 0, stream,
                       vdup, off16, at16, refpts, spatial, lsi, samp16);

    hipLaunchKernelGGL(gemm_out, dim3(2, mBlocks), blk256, 0, stream,
                       samp16, woutT, bout, (float*)d_out, MTOT, 256);
}